// Round 6
// baseline (273.121 us; speedup 1.0000x reference)
//
#include <hip/hip_runtime.h>
#include <hip/hip_fp16.h>

typedef __attribute__((ext_vector_type(8))) _Float16 f16x8;
typedef __attribute__((ext_vector_type(4))) float f32x4;
typedef __attribute__((ext_vector_type(16))) float f32x16;

#define M_TOT 8192
#define N_TOT 8192
#define K_TOT 256

// ---------- helpers ----------
__device__ __forceinline__ unsigned long long shfl_xor_u64(unsigned long long v, int m) {
  unsigned lo = (unsigned)v, hi = (unsigned)(v >> 32);
  lo = __shfl_xor(lo, m, 64);
  hi = __shfl_xor(hi, m, 64);
  return (((unsigned long long)hi) << 32) | lo;
}
__device__ __forceinline__ void load_lds16(const void* g, void* l) {
  __builtin_amdgcn_global_load_lds(
      (const __attribute__((address_space(1))) unsigned int*)g,
      (__attribute__((address_space(3))) unsigned int*)l, 16, 0, 0);
}

// ---------- fused prep: split-2 (fp16) of x AND embed, + ||e||^2, + key init ----------
// x = h0 + h1 + rho, |rho| ~ 2^-22|x|; dropped cross-terms give |err(dist2)| ~ 1e-5
// vs min-gap O(10) -> argmin-exact with huge margin (bf16 split-2 was ~2.4e-4).
__global__ __launch_bounds__(256) void prep_kernel(
    const float* __restrict__ x, const float* __restrict__ embed,
    unsigned short* __restrict__ X0, unsigned short* __restrict__ X1,
    unsigned short* __restrict__ E0, unsigned short* __restrict__ E1,
    float* __restrict__ esq, unsigned long long* __restrict__ keys) {
  const int bid = blockIdx.x;
  const bool is_e = bid >= 2048;
  const int lb = is_e ? bid - 2048 : bid;
  const int t = lb * 256 + threadIdx.x;
  if (bid < 32) keys[t] = ~0ULL;  // 8192 keys

  const float* __restrict__ in = is_e ? embed : x;
  unsigned short* __restrict__ s0 = is_e ? E0 : X0;
  unsigned short* __restrict__ s1 = is_e ? E1 : X1;

  float4 v = reinterpret_cast<const float4*>(in)[t];
  float f[4] = {v.x, v.y, v.z, v.w};
  unsigned short a0[4], a1[4];
#pragma unroll
  for (int c = 0; c < 4; ++c) {
    __half h0 = __float2half_rn(f[c]);
    float r1 = f[c] - __half2float(h0);  // exact (Sterbenz)
    __half h1 = __float2half_rn(r1);
    a0[c] = __half_as_ushort(h0);
    a1[c] = __half_as_ushort(h1);
  }
  ushort4 o0 = {a0[0], a0[1], a0[2], a0[3]};
  ushort4 o1 = {a1[0], a1[1], a1[2], a1[3]};
  reinterpret_cast<ushort4*>(s0)[t] = o0;
  reinterpret_cast<ushort4*>(s1)[t] = o1;

  if (is_e) {
    const int lane = threadIdx.x & 63;
    float s = f[0] * f[0] + f[1] * f[1] + f[2] * f[2] + f[3] * f[3];
#pragma unroll
    for (int off = 32; off > 0; off >>= 1) s += __shfl_xor(s, off, 64);
    if (lane == 0) esq[lb * 4 + (threadIdx.x >> 6)] = s;  // wave == e-row
  }
}

// ---------- fused split-2 fp16 MFMA dist-GEMM + argmin, double-buffered ----------
// 128x128 tile, 4 waves 2x2, wave tile 64x64 = 2x2 of 32x32x16_f16.
// 3 passes: x0e0, x0e1, x1e0.  LDS: 2 x 32 KB buffers (X0,X1,E0,E1 x 8 segs).
// Dbuf K-loop: barrier; issue chunk k+1 into other buffer; compute chunk k.
// -> the barrier's vmcnt(0) drain waits on loads issued a FULL chunk earlier
// (overlapped), killing the serial staging phase of the 2-barrier structure.
// (256,2): reg cap 256; need ~150 (64 AGPR acc + ~90 VGPR) -> no spill
// (round-3 lesson: watch WRITE_SIZE; spill showed as GBs of scratch traffic).
__global__ __launch_bounds__(256, 2) void mfma_argmin_kernel(
    const unsigned short* __restrict__ X0, const unsigned short* __restrict__ X1,
    const unsigned short* __restrict__ E0, const unsigned short* __restrict__ E1,
    const float* __restrict__ esq, unsigned long long* __restrict__ keys) {
  __shared__ unsigned short lds[2][16384];  // 2 x 32 KB

  const int tid = threadIdx.x;
  const int wid = tid >> 6;
  const int lane = tid & 63;
  const int li = lane & 15;
  const int lh = (lane >> 4) & 1;  // 16-row half within a 32-row MFMA tile
  const int lq2 = lane >> 5;       // k-group within frag

  // XCD-sharded N: blocks with same (bid&7) share an E-slice (L2-resident)
  const int bid = blockIdx.x;
  const int nb = (bid & 7) * 8 + ((bid >> 3) & 7);  // 0..63
  const int mb = bid >> 6;                          // 0..63
  const int m0 = mb * 128, n0 = nb * 128;
  const int wm = (wid >> 1) * 64, wn = (wid & 1) * 64;

  // staging: lane -> (row-in-segment, k-part) inverse swizzle
  const int r_st = lane >> 2;
  const int kp_st = ((lane & 3) - (r_st >> 1)) & 3;
  // frag read swizzle (ushort offset within a 512-ushort segment), k-slice 0/1
  const int sw_k0 = (li * 4 + ((lq2 + (li >> 1)) & 3)) * 8;
  const int sw_k1 = (li * 4 + ((2 + lq2 + (li >> 1)) & 3)) * 8;

  const unsigned short* __restrict__ srcs[4] = {X0, X1, E0, E1};

  f32x16 acc[2][2];
#pragma unroll
  for (int a = 0; a < 2; ++a)
#pragma unroll
    for (int b = 0; b < 2; ++b)
#pragma unroll
      for (int r = 0; r < 16; ++r) acc[a][b][r] = 0.0f;

  const int aseg = (wm >> 4) + lh;  // + mt*2
  const int bseg = (wn >> 4) + lh;  // + nt*2

  // ---- stage chunk 0 into buffer 0 ----
#pragma unroll
  for (int j = 0; j < 8; ++j) {
    const int tt = j * 4 + wid;   // wave-uniform
    const int tsel = tt >> 3;     // 0=X0 1=X1 2=E0 3=E1
    const int seg = tt & 7;
    const int rowbase = ((tsel >= 2) ? n0 : m0) + seg * 16 + r_st;
    load_lds16(srcs[tsel] + (size_t)rowbase * K_TOT + kp_st * 8,
               &lds[0][tsel * 4096 + seg * 512]);
  }

  for (int kc = 0; kc < 8; ++kc) {
    __syncthreads();  // drains chunk-kc loads (issued one full chunk ago)
    if (kc < 7) {
      const int k0n = (kc + 1) * 32;
      unsigned short* dst = lds[(kc + 1) & 1];
#pragma unroll
      for (int j = 0; j < 8; ++j) {
        const int tt = j * 4 + wid;
        const int tsel = tt >> 3;
        const int seg = tt & 7;
        const int rowbase = ((tsel >= 2) ? n0 : m0) + seg * 16 + r_st;
        load_lds16(srcs[tsel] + (size_t)rowbase * K_TOT + k0n + kp_st * 8,
                   dst + tsel * 4096 + seg * 512);
      }
    }
    const unsigned short* buf = lds[kc & 1];

    // A-frags: [split][mt][ks]
    f16x8 afr[2][2][2];
#pragma unroll
    for (int s = 0; s < 2; ++s)
#pragma unroll
      for (int mt = 0; mt < 2; ++mt) {
        const unsigned short* ab = buf + s * 4096 + (aseg + mt * 2) * 512;
        afr[s][mt][0] = *(const f16x8*)(ab + sw_k0);
        afr[s][mt][1] = *(const f16x8*)(ab + sw_k1);
      }

#pragma unroll
    for (int nt = 0; nt < 2; ++nt) {
      const unsigned short* b0b = buf + 8192 + (bseg + nt * 2) * 512;
      const unsigned short* b1b = b0b + 4096;
      f16x8 b00 = *(const f16x8*)(b0b + sw_k0);  // E0, ks0
      f16x8 b01 = *(const f16x8*)(b0b + sw_k1);  // E0, ks1
      f16x8 b10 = *(const f16x8*)(b1b + sw_k0);  // E1, ks0
      f16x8 b11 = *(const f16x8*)(b1b + sw_k1);  // E1, ks1
#pragma unroll
      for (int mt = 0; mt < 2; ++mt) {
        f32x16 c = acc[mt][nt];
        c = __builtin_amdgcn_mfma_f32_32x32x16_f16(afr[0][mt][0], b00, c, 0, 0, 0);
        c = __builtin_amdgcn_mfma_f32_32x32x16_f16(afr[0][mt][1], b01, c, 0, 0, 0);
        c = __builtin_amdgcn_mfma_f32_32x32x16_f16(afr[0][mt][0], b10, c, 0, 0, 0);
        c = __builtin_amdgcn_mfma_f32_32x32x16_f16(afr[0][mt][1], b11, c, 0, 0, 0);
        c = __builtin_amdgcn_mfma_f32_32x32x16_f16(afr[1][mt][0], b00, c, 0, 0, 0);
        c = __builtin_amdgcn_mfma_f32_32x32x16_f16(afr[1][mt][1], b01, c, 0, 0, 0);
        acc[mt][nt] = c;
      }
    }
  }

  // ---- argmin epilogue: dist = ||e||^2 - 2 x.e ----
  // 32x32 C/D layout (m74/m101): col = lane&31, row = (r&3)+8*(r>>2)+4*(lane>>5)
  const int colbase = n0 + wn + (lane & 31);
  float ev[2];
#pragma unroll
  for (int nt = 0; nt < 2; ++nt) ev[nt] = esq[colbase + nt * 32];

#pragma unroll
  for (int mt = 0; mt < 2; ++mt) {
#pragma unroll
    for (int r = 0; r < 16; ++r) {
      unsigned long long best = ~0ULL;
#pragma unroll
      for (int nt = 0; nt < 2; ++nt) {
        float d = fmaxf(ev[nt] - 2.0f * acc[mt][nt][r], 0.0f);  // >=0 -> bits order-preserving
        unsigned long long key =
            (((unsigned long long)__float_as_uint(d)) << 32) | (unsigned)(colbase + nt * 32);
        best = key < best ? key : best;
      }
#pragma unroll
      for (int off = 1; off < 32; off <<= 1) {  // reduce over 32 col-lanes
        unsigned long long o = shfl_xor_u64(best, off);
        best = o < best ? o : best;
      }
      if ((lane & 31) == 0) {
        const int m = m0 + wm + mt * 32 + (r & 3) + 8 * (r >> 2) + 4 * lq2;
        atomicMin(&keys[m], best);  // tie -> lower idx = first occurrence
      }
    }
  }
}

// ---------- gather + index write (4 rows per block) ----------
__global__ __launch_bounds__(256) void gather2_kernel(const float* __restrict__ embed,
                                                      const unsigned long long* __restrict__ keys,
                                                      float* __restrict__ out) {
  const int row = blockIdx.x * 4 + (threadIdx.x >> 6);
  const int lane = threadIdx.x & 63;
  const unsigned idx = (unsigned)keys[row];
  reinterpret_cast<float4*>(out)[(size_t)row * 64 + lane] =
      reinterpret_cast<const float4*>(embed)[(size_t)idx * 64 + lane];
  if (lane == 0) out[(size_t)M_TOT * K_TOT + row] = (float)idx;
}

// ================= fallback (round-1 fp32 path, known-correct) =================
#define BM 32
#define BN 64
#define KC 32
#define NQ 2
#define NPQ (N_TOT / NQ)
#define SB 72

__global__ __launch_bounds__(256) void esq_kernel(const float* __restrict__ embed,
                                                  float* __restrict__ esq) {
  const int lane = threadIdx.x & 63;
  const int wave = threadIdx.x >> 6;
  const int code = blockIdx.x * 4 + wave;
  float4 v = reinterpret_cast<const float4*>(embed + (size_t)code * K_TOT)[lane];
  float s = v.x * v.x + v.y * v.y + v.z * v.z + v.w * v.w;
#pragma unroll
  for (int off = 32; off > 0; off >>= 1) s += __shfl_xor(s, off, 64);
  if (lane == 0) esq[code] = s;
}

__global__ __launch_bounds__(256, 2) void argmin_kernel(
    const float* __restrict__ x, const float* __restrict__ embed,
    const float* __restrict__ esq, float* __restrict__ pval, int* __restrict__ pidx) {
  __shared__ float A[K_TOT][BM];
  __shared__ float Bs[KC][SB];
  const int tid = threadIdx.x;
  const int tx = tid & 15;
  const int ty = tid >> 4;
  const int q = blockIdx.x & 1;
  const int mb = blockIdx.x >> 1;
  const int m0 = mb * BM;
  const int nq0 = q * NPQ;
#pragma unroll
  for (int it = 0; it < 8; ++it) {
    int idx = it * 256 + tid;
    int row = idx >> 6;
    int k4 = idx & 63;
    float4 v = reinterpret_cast<const float4*>(x + (size_t)(m0 + row) * K_TOT)[k4];
    A[k4 * 4 + 0][row] = v.x; A[k4 * 4 + 1][row] = v.y;
    A[k4 * 4 + 2][row] = v.z; A[k4 * 4 + 3][row] = v.w;
  }
  float minv[2]; int mini[2];
#pragma unroll
  for (int r = 0; r < 2; ++r) { minv[r] = 3.4e38f; mini[r] = 0; }
  for (int ns = 0; ns < NPQ / BN; ++ns) {
    const int n0 = nq0 + ns * BN;
    float acc[2][4];
#pragma unroll
    for (int r = 0; r < 2; ++r)
#pragma unroll
      for (int c = 0; c < 4; ++c) acc[r][c] = 0.0f;
    for (int kc = 0; kc < K_TOT / KC; ++kc) {
      const int k0 = kc * KC;
      __syncthreads();
#pragma unroll
      for (int it = 0; it < 2; ++it) {
        int idx = it * 256 + tid;
        int nl = idx >> 3;
        int k4 = idx & 7;
        float4 v = reinterpret_cast<const float4*>(embed + (size_t)(n0 + nl) * K_TOT + k0)[k4];
        Bs[k4 * 4 + 0][nl] = v.x; Bs[k4 * 4 + 1][nl] = v.y;
        Bs[k4 * 4 + 2][nl] = v.z; Bs[k4 * 4 + 3][nl] = v.w;
      }
      __syncthreads();
#pragma unroll
      for (int kk = 0; kk < KC; ++kk) {
        float2 a = *reinterpret_cast<const float2*>(&A[k0 + kk][ty * 2]);
        float4 b = *reinterpret_cast<const float4*>(&Bs[kk][tx * 4]);
        acc[0][0] += a.x * b.x; acc[0][1] += a.x * b.y;
        acc[0][2] += a.x * b.z; acc[0][3] += a.x * b.w;
        acc[1][0] += a.y * b.x; acc[1][1] += a.y * b.y;
        acc[1][2] += a.y * b.z; acc[1][3] += a.y * b.w;
      }
    }
    float4 es = *reinterpret_cast<const float4*>(&esq[n0 + tx * 4]);
    float e[4] = {es.x, es.y, es.z, es.w};
#pragma unroll
    for (int r = 0; r < 2; ++r)
#pragma unroll
      for (int c = 0; c < 4; ++c) {
        float d = e[c] - 2.0f * acc[r][c];
        int id = n0 + tx * 4 + c;
        if (d < minv[r]) { minv[r] = d; mini[r] = id; }
      }
  }
#pragma unroll
  for (int r = 0; r < 2; ++r) {
    float v = minv[r]; int i = mini[r];
#pragma unroll
    for (int off = 1; off < 16; off <<= 1) {
      float vo = __shfl_xor(v, off, 64);
      int io = __shfl_xor(i, off, 64);
      if (vo < v || (vo == v && io < i)) { v = vo; i = io; }
    }
    if (tx == 0) {
      int row = m0 + ty * 2 + r;
      pval[q * M_TOT + row] = v;
      pidx[q * M_TOT + row] = i;
    }
  }
}

__global__ __launch_bounds__(256) void gather_kernel(
    const float* __restrict__ embed, const float* __restrict__ pval,
    const int* __restrict__ pidx, float* __restrict__ out) {
  const int row = blockIdx.x;
  float bv = pval[row]; int bi = pidx[row];
#pragma unroll
  for (int qq = 1; qq < NQ; ++qq) {
    float v = pval[qq * M_TOT + row];
    int i = pidx[qq * M_TOT + row];
    if (v < bv || (v == bv && i < bi)) { bv = v; bi = i; }
  }
  out[(size_t)row * K_TOT + threadIdx.x] = embed[(size_t)bi * K_TOT + threadIdx.x];
  if (threadIdx.x == 0) out[(size_t)M_TOT * K_TOT + row] = (float)bi;
}

// ================= launch =================
extern "C" void kernel_launch(void* const* d_in, const int* in_sizes, int n_in,
                              void* d_out, int out_size, void* d_ws, size_t ws_size,
                              hipStream_t stream) {
  const float* x = (const float*)d_in[0];
  const float* embed = (const float*)d_in[1];
  float* out = (float*)d_out;
  char* ws = (char*)d_ws;

  const size_t SPLIT_BYTES = (size_t)M_TOT * K_TOT * 2;  // 4 MB per split matrix
  const size_t need = (1u << 20) + 4 * SPLIT_BYTES;      // ~17.8 MB

  if (ws_size >= need) {
    unsigned long long* keys = (unsigned long long*)ws;  // 64 KB
    float* esq = (float*)(ws + 65536);                   // 32 KB
    unsigned short* S[4];
    for (int i = 0; i < 4; ++i) S[i] = (unsigned short*)(ws + (1u << 20) + i * SPLIT_BYTES);
    prep_kernel<<<4096, 256, 0, stream>>>(x, embed, S[0], S[1], S[2], S[3], esq, keys);
    mfma_argmin_kernel<<<4096, 256, 0, stream>>>(S[0], S[1], S[2], S[3], esq, keys);
    gather2_kernel<<<2048, 256, 0, stream>>>(embed, keys, out);
  } else {
    float* esq = (float*)ws;
    float* pval = (float*)(ws + 32768);
    int* pidx = (int*)(ws + 32768 + NQ * 32768);
    esq_kernel<<<2048, 256, 0, stream>>>(embed, esq);
    argmin_kernel<<<512, 256, 0, stream>>>(x, embed, esq, pval, pidx);
    gather_kernel<<<M_TOT, 256, 0, stream>>>(embed, pval, pidx, out);
  }
}

// Round 7
// 261.970 us; speedup vs baseline: 1.0426x; 1.0426x over previous
//
#include <hip/hip_runtime.h>
#include <hip/hip_fp16.h>

typedef __attribute__((ext_vector_type(8))) _Float16 f16x8;
typedef __attribute__((ext_vector_type(16))) float f32x16;

#define M_TOT 8192
#define N_TOT 8192
#define K_TOT 256

// ---------- helpers ----------
__device__ __forceinline__ unsigned long long shfl_xor_u64(unsigned long long v, int m) {
  unsigned lo = (unsigned)v, hi = (unsigned)(v >> 32);
  lo = __shfl_xor(lo, m, 64);
  hi = __shfl_xor(hi, m, 64);
  return (((unsigned long long)hi) << 32) | lo;
}

// ---------- pack: fp16 split-2 into MFMA-fragment-major layout ----------
// Fragment layout for v_mfma_f32_32x32x16_f16 A/B operands (verified r4/r5):
//   lane l holds M[tile*32 + (l&31)][ks*16 + (l>>5)*8 + j], j=0..7  (16B/lane)
// packed[tile][ks] is a 1KB block, lane-contiguous -> frag load is ONE
// perfectly-coalesced global_load_dwordx4. Also: keys init (X half) and
// fp32 ||e||^2 (E half).
__global__ __launch_bounds__(256) void pack_kernel(
    const float* __restrict__ x, const float* __restrict__ embed,
    unsigned short* __restrict__ X0p, unsigned short* __restrict__ X1p,
    unsigned short* __restrict__ E0p, unsigned short* __restrict__ E1p,
    float* __restrict__ esq, unsigned long long* __restrict__ keys) {
  const int bid = blockIdx.x;
  const bool is_e = bid >= 1024;
  const int lb = is_e ? bid - 1024 : bid;
  const int t = lb * 256 + threadIdx.x;  // 0..262143 ; 8 elems each
  if (bid < 32) keys[t] = ~0ULL;

  const float* __restrict__ in = is_e ? embed : x;
  unsigned short* __restrict__ p0 = is_e ? E0p : X0p;
  unsigned short* __restrict__ p1 = is_e ? E1p : X1p;

  const int m = t >> 5;   // row
  const int g = t & 31;   // k-group of 8
  float4 v0 = *reinterpret_cast<const float4*>(in + (size_t)m * K_TOT + g * 8);
  float4 v1 = *reinterpret_cast<const float4*>(in + (size_t)m * K_TOT + g * 8 + 4);
  float f[8] = {v0.x, v0.y, v0.z, v0.w, v1.x, v1.y, v1.z, v1.w};
  unsigned short h0[8], h1[8];
#pragma unroll
  for (int c = 0; c < 8; ++c) {
    __half a = __float2half_rn(f[c]);
    float r1 = f[c] - __half2float(a);  // exact residual
    h0[c] = __half_as_ushort(a);
    h1[c] = __half_as_ushort(__float2half_rn(r1));
  }
  const int ks = g >> 1;
  const int lane = (m & 31) + (g & 1) * 32;
  const size_t off = ((size_t)((m >> 5) * 16 + ks)) * 512 + lane * 8;  // ushorts
  *reinterpret_cast<int4*>(p0 + off) = *reinterpret_cast<int4*>(h0);
  *reinterpret_cast<int4*>(p1 + off) = *reinterpret_cast<int4*>(h1);

  if (is_e) {
    float s = 0.f;
#pragma unroll
    for (int c = 0; c < 8; ++c) s += f[c] * f[c];
#pragma unroll
    for (int off2 = 1; off2 < 32; off2 <<= 1) s += __shfl_xor(s, off2, 64);  // 32-lane group
    if ((threadIdx.x & 31) == 0) esq[m] = s;  // row == t>>5, lanes 0/32 hold the 2 rows
  }
}

// ---------- no-LDS fragment-streaming MFMA dist-GEMM + argmin ----------
// NO __shared__, NO barriers: every A/B fragment is a coalesced 16B/lane
// global load from the packed (fragment-major) tensors; L1 dedups across the
// 2x2 wave arrangement, L2 serves the rest (41 B/cyc/CU needed < 56 budget).
// K-loop: 16 k-steps, register ping-pong prefetch (load ks+1, MFMA ks) ->
// loads have a full MFMA phase (~390 SIMD-cyc) to complete; no vmcnt(0) drain.
// 3 passes: x0e0 + x0e1 + x1e0 (fp16 split-2, |err dist2| ~1e-5, gap O(5)).
// Regs: acc 64 AGPR + ~64 VGPR frags + addr -> ~150 < 170 cap => (256,3), no
// spill (r3 lesson: spill => GBs in WRITE_SIZE; check it stays ~16MB).
__global__ __launch_bounds__(256, 3) void mfma_argmin_kernel(
    const unsigned short* __restrict__ X0p, const unsigned short* __restrict__ X1p,
    const unsigned short* __restrict__ E0p, const unsigned short* __restrict__ E1p,
    const float* __restrict__ esq, unsigned long long* __restrict__ keys) {
  const int tid = threadIdx.x;
  const int wid = tid >> 6;
  const int lane = tid & 63;

  // XCD 4x2 patch shard: each XCD owns a 16mb x 32nb patch of 128x128 tiles
  // (A-slice 2MB + B-slice 4MB stay in its L2; HBM refetch ~50MB total).
  const int bid = blockIdx.x;
  const int xcd = bid & 7;
  const int w = bid >> 3;                  // 0..511
  const int mb = (xcd >> 1) * 16 + (w >> 5);  // 0..63
  const int nb = (xcd & 1) * 32 + (w & 31);   // 0..63
  const int mt2 = wid >> 1, nt2 = wid & 1;    // 2x2 waves: A shared by wave pairs (L1)
  const int am0 = mb * 4 + mt2 * 2;        // 32-row A-tile index (and +1)
  const int bn0 = nb * 4 + nt2 * 2;        // 32-col B-tile index (and +1)

  const size_t lo = (size_t)lane * 8;      // ushort offset within a frag
  const unsigned short* __restrict__ A0 = X0p + (size_t)am0 * 8192 + lo;  // tile stride 16*512
  const unsigned short* __restrict__ A1 = X1p + (size_t)am0 * 8192 + lo;
  const unsigned short* __restrict__ B0 = E0p + (size_t)bn0 * 8192 + lo;
  const unsigned short* __restrict__ B1 = E1p + (size_t)bn0 * 8192 + lo;

  f32x16 acc[2][2];
#pragma unroll
  for (int a = 0; a < 2; ++a)
#pragma unroll
    for (int b = 0; b < 2; ++b)
#pragma unroll
      for (int r = 0; r < 16; ++r) acc[a][b][r] = 0.0f;

  f16x8 fa0[2][2], fa1[2][2], fb0[2][2], fb1[2][2];  // [buf][tile]
  // preload ks=0 into buf 0
#pragma unroll
  for (int tl = 0; tl < 2; ++tl) {
    fa0[0][tl] = *(const f16x8*)(A0 + (size_t)tl * 8192);
    fa1[0][tl] = *(const f16x8*)(A1 + (size_t)tl * 8192);
    fb0[0][tl] = *(const f16x8*)(B0 + (size_t)tl * 8192);
    fb1[0][tl] = *(const f16x8*)(B1 + (size_t)tl * 8192);
  }

#pragma unroll
  for (int ks = 0; ks < 16; ++ks) {
    const int cur = ks & 1, nxt = cur ^ 1;
    if (ks < 15) {
      const size_t o = (size_t)(ks + 1) * 512;
#pragma unroll
      for (int tl = 0; tl < 2; ++tl) {
        fa0[nxt][tl] = *(const f16x8*)(A0 + o + (size_t)tl * 8192);
        fa1[nxt][tl] = *(const f16x8*)(A1 + o + (size_t)tl * 8192);
        fb0[nxt][tl] = *(const f16x8*)(B0 + o + (size_t)tl * 8192);
        fb1[nxt][tl] = *(const f16x8*)(B1 + o + (size_t)tl * 8192);
      }
    }
#pragma unroll
    for (int mt = 0; mt < 2; ++mt)
#pragma unroll
      for (int nt = 0; nt < 2; ++nt) {
        f32x16 c = acc[mt][nt];
        c = __builtin_amdgcn_mfma_f32_32x32x16_f16(fa0[cur][mt], fb0[cur][nt], c, 0, 0, 0);
        c = __builtin_amdgcn_mfma_f32_32x32x16_f16(fa0[cur][mt], fb1[cur][nt], c, 0, 0, 0);
        c = __builtin_amdgcn_mfma_f32_32x32x16_f16(fa1[cur][mt], fb0[cur][nt], c, 0, 0, 0);
        acc[mt][nt] = c;
      }
  }

  // ---- argmin epilogue: dist = ||e||^2 - 2 x.e ----
  // 32x32 C/D layout (m74/m101, r5-verified): col = lane&31,
  // row = (r&3) + 8*(r>>2) + 4*(lane>>5)
  const int m0w = mb * 128 + mt2 * 64;
  const int n0w = nb * 128 + nt2 * 64;
  const int colbase = n0w + (lane & 31);
  float ev[2];
#pragma unroll
  for (int nt = 0; nt < 2; ++nt) ev[nt] = esq[colbase + nt * 32];

#pragma unroll
  for (int mt = 0; mt < 2; ++mt) {
#pragma unroll
    for (int r = 0; r < 16; ++r) {
      unsigned long long best = ~0ULL;
#pragma unroll
      for (int nt = 0; nt < 2; ++nt) {
        float d = fmaxf(ev[nt] - 2.0f * acc[mt][nt][r], 0.0f);  // >=0 -> bits order-preserving
        unsigned long long key =
            (((unsigned long long)__float_as_uint(d)) << 32) | (unsigned)(colbase + nt * 32);
        best = key < best ? key : best;
      }
#pragma unroll
      for (int off = 1; off < 32; off <<= 1) {  // min over the 32 col-lanes
        unsigned long long o = shfl_xor_u64(best, off);
        best = o < best ? o : best;
      }
      if ((lane & 31) == 0) {
        const int m = m0w + mt * 32 + (r & 3) + 8 * (r >> 2) + 4 * (lane >> 5);
        atomicMin(&keys[m], best);  // tie -> lower idx = first occurrence
      }
    }
  }
}

// ---------- gather + index write (4 rows per block) ----------
__global__ __launch_bounds__(256) void gather2_kernel(const float* __restrict__ embed,
                                                      const unsigned long long* __restrict__ keys,
                                                      float* __restrict__ out) {
  const int row = blockIdx.x * 4 + (threadIdx.x >> 6);
  const int lane = threadIdx.x & 63;
  const unsigned idx = (unsigned)keys[row];
  reinterpret_cast<float4*>(out)[(size_t)row * 64 + lane] =
      reinterpret_cast<const float4*>(embed)[(size_t)idx * 64 + lane];
  if (lane == 0) out[(size_t)M_TOT * K_TOT + row] = (float)idx;
}

// ================= fallback (round-1 fp32 path, known-correct) =================
#define BM 32
#define BN 64
#define KC 32
#define NQ 2
#define NPQ (N_TOT / NQ)
#define SB 72

__global__ __launch_bounds__(256) void esq_kernel(const float* __restrict__ embed,
                                                  float* __restrict__ esq) {
  const int lane = threadIdx.x & 63;
  const int wave = threadIdx.x >> 6;
  const int code = blockIdx.x * 4 + wave;
  float4 v = reinterpret_cast<const float4*>(embed + (size_t)code * K_TOT)[lane];
  float s = v.x * v.x + v.y * v.y + v.z * v.z + v.w * v.w;
#pragma unroll
  for (int off = 32; off > 0; off >>= 1) s += __shfl_xor(s, off, 64);
  if (lane == 0) esq[code] = s;
}

__global__ __launch_bounds__(256, 2) void argmin_kernel(
    const float* __restrict__ x, const float* __restrict__ embed,
    const float* __restrict__ esq, float* __restrict__ pval, int* __restrict__ pidx) {
  __shared__ float A[K_TOT][BM];
  __shared__ float Bs[KC][SB];
  const int tid = threadIdx.x;
  const int tx = tid & 15;
  const int ty = tid >> 4;
  const int q = blockIdx.x & 1;
  const int mb = blockIdx.x >> 1;
  const int m0 = mb * BM;
  const int nq0 = q * NPQ;
#pragma unroll
  for (int it = 0; it < 8; ++it) {
    int idx = it * 256 + tid;
    int row = idx >> 6;
    int k4 = idx & 63;
    float4 v = reinterpret_cast<const float4*>(x + (size_t)(m0 + row) * K_TOT)[k4];
    A[k4 * 4 + 0][row] = v.x; A[k4 * 4 + 1][row] = v.y;
    A[k4 * 4 + 2][row] = v.z; A[k4 * 4 + 3][row] = v.w;
  }
  float minv[2]; int mini[2];
#pragma unroll
  for (int r = 0; r < 2; ++r) { minv[r] = 3.4e38f; mini[r] = 0; }
  for (int ns = 0; ns < NPQ / BN; ++ns) {
    const int n0 = nq0 + ns * BN;
    float acc[2][4];
#pragma unroll
    for (int r = 0; r < 2; ++r)
#pragma unroll
      for (int c = 0; c < 4; ++c) acc[r][c] = 0.0f;
    for (int kc = 0; kc < K_TOT / KC; ++kc) {
      const int k0 = kc * KC;
      __syncthreads();
#pragma unroll
      for (int it = 0; it < 2; ++it) {
        int idx = it * 256 + tid;
        int nl = idx >> 3;
        int k4 = idx & 7;
        float4 v = reinterpret_cast<const float4*>(embed + (size_t)(n0 + nl) * K_TOT + k0)[k4];
        Bs[k4 * 4 + 0][nl] = v.x; Bs[k4 * 4 + 1][nl] = v.y;
        Bs[k4 * 4 + 2][nl] = v.z; Bs[k4 * 4 + 3][nl] = v.w;
      }
      __syncthreads();
#pragma unroll
      for (int kk = 0; kk < KC; ++kk) {
        float2 a = *reinterpret_cast<const float2*>(&A[k0 + kk][ty * 2]);
        float4 b = *reinterpret_cast<const float4*>(&Bs[kk][tx * 4]);
        acc[0][0] += a.x * b.x; acc[0][1] += a.x * b.y;
        acc[0][2] += a.x * b.z; acc[0][3] += a.x * b.w;
        acc[1][0] += a.y * b.x; acc[1][1] += a.y * b.y;
        acc[1][2] += a.y * b.z; acc[1][3] += a.y * b.w;
      }
    }
    float4 es = *reinterpret_cast<const float4*>(&esq[n0 + tx * 4]);
    float e[4] = {es.x, es.y, es.z, es.w};
#pragma unroll
    for (int r = 0; r < 2; ++r)
#pragma unroll
      for (int c = 0; c < 4; ++c) {
        float d = e[c] - 2.0f * acc[r][c];
        int id = n0 + tx * 4 + c;
        if (d < minv[r]) { minv[r] = d; mini[r] = id; }
      }
  }
#pragma unroll
  for (int r = 0; r < 2; ++r) {
    float v = minv[r]; int i = mini[r];
#pragma unroll
    for (int off = 1; off < 16; off <<= 1) {
      float vo = __shfl_xor(v, off, 64);
      int io = __shfl_xor(i, off, 64);
      if (vo < v || (vo == v && io < i)) { v = vo; i = io; }
    }
    if (tx == 0) {
      int row = m0 + ty * 2 + r;
      pval[q * M_TOT + row] = v;
      pidx[q * M_TOT + row] = i;
    }
  }
}

__global__ __launch_bounds__(256) void gather_kernel(
    const float* __restrict__ embed, const float* __restrict__ pval,
    const int* __restrict__ pidx, float* __restrict__ out) {
  const int row = blockIdx.x;
  float bv = pval[row]; int bi = pidx[row];
#pragma unroll
  for (int qq = 1; qq < NQ; ++qq) {
    float v = pval[qq * M_TOT + row];
    int i = pidx[qq * M_TOT + row];
    if (v < bv || (v == bv && i < bi)) { bv = v; bi = i; }
  }
  out[(size_t)row * K_TOT + threadIdx.x] = embed[(size_t)bi * K_TOT + threadIdx.x];
  if (threadIdx.x == 0) out[(size_t)M_TOT * K_TOT + row] = (float)bi;
}

// ================= launch =================
extern "C" void kernel_launch(void* const* d_in, const int* in_sizes, int n_in,
                              void* d_out, int out_size, void* d_ws, size_t ws_size,
                              hipStream_t stream) {
  const float* x = (const float*)d_in[0];
  const float* embed = (const float*)d_in[1];
  float* out = (float*)d_out;
  char* ws = (char*)d_ws;

  const size_t SPLIT_BYTES = (size_t)M_TOT * K_TOT * 2;  // 4 MB per packed matrix
  const size_t need = (1u << 20) + 4 * SPLIT_BYTES;      // ~17.8 MB

  if (ws_size >= need) {
    unsigned long long* keys = (unsigned long long*)ws;  // 64 KB
    float* esq = (float*)(ws + 65536);                   // 32 KB
    unsigned short* S[4];
    for (int i = 0; i < 4; ++i) S[i] = (unsigned short*)(ws + (1u << 20) + i * SPLIT_BYTES);
    pack_kernel<<<2048, 256, 0, stream>>>(x, embed, S[0], S[1], S[2], S[3], esq, keys);
    mfma_argmin_kernel<<<4096, 256, 0, stream>>>(S[0], S[1], S[2], S[3], esq, keys);
    gather2_kernel<<<2048, 256, 0, stream>>>(embed, keys, out);
  } else {
    float* esq = (float*)ws;
    float* pval = (float*)(ws + 32768);
    int* pidx = (int*)(ws + 32768 + NQ * 32768);
    esq_kernel<<<2048, 256, 0, stream>>>(embed, esq);
    argmin_kernel<<<512, 256, 0, stream>>>(x, embed, esq, pval, pidx);
    gather_kernel<<<M_TOT, 256, 0, stream>>>(embed, pval, pidx, out);
  }
}

// Round 8
// 222.821 us; speedup vs baseline: 1.2257x; 1.1757x over previous
//
#include <hip/hip_runtime.h>
#include <hip/hip_fp16.h>

typedef __attribute__((ext_vector_type(8))) _Float16 f16x8;
typedef __attribute__((ext_vector_type(16))) float f32x16;

#define M_TOT 8192
#define N_TOT 8192
#define K_TOT 256

__device__ __forceinline__ void load_lds16(const void* g, void* l) {
  __builtin_amdgcn_global_load_lds(
      (const __attribute__((address_space(1))) unsigned int*)g,
      (__attribute__((address_space(3))) unsigned int*)l, 16, 0, 0);
}

// ---------- prep: fp16 convert (row-major) + row sq-norms ----------
// blocks 0..2047: x -> X0p + xsq ; blocks 2048..4095: embed -> E0p + esq
__global__ __launch_bounds__(256) void prep_kernel(
    const float* __restrict__ x, const float* __restrict__ embed,
    unsigned short* __restrict__ X0p, unsigned short* __restrict__ E0p,
    float* __restrict__ xsq, float* __restrict__ esq) {
  const int bid = blockIdx.x;
  const bool is_e = bid >= 2048;
  const int lb = is_e ? bid - 2048 : bid;
  const int t = lb * 256 + threadIdx.x;  // 4 elems per thread; wave == row
  const float* __restrict__ in = is_e ? embed : x;
  unsigned short* __restrict__ p0 = is_e ? E0p : X0p;
  float* __restrict__ sq = is_e ? esq : xsq;

  float4 v = reinterpret_cast<const float4*>(in)[t];
  float f[4] = {v.x, v.y, v.z, v.w};
  unsigned short h[4];
#pragma unroll
  for (int c = 0; c < 4; ++c) h[c] = __half_as_ushort(__float2half_rn(f[c]));
  ushort4 o = {h[0], h[1], h[2], h[3]};
  reinterpret_cast<ushort4*>(p0)[t] = o;

  const int lane = threadIdx.x & 63;
  float s = f[0] * f[0] + f[1] * f[1] + f[2] * f[2] + f[3] * f[3];
#pragma unroll
  for (int off = 32; off > 0; off >>= 1) s += __shfl_xor(s, off, 64);
  if (lane == 0) sq[lb * 4 + (threadIdx.x >> 6)] = s;
}

// ---------- phase-1: single-pass fp16 MFMA dist-GEMM -> per-cell minima ----------
// 128x128 tile, 4 waves 2x2, wave 64x64 = 2x2 of 32x32x16_f16, BK=32, LDS 16 KB.
// Same verified swizzled global_load_lds staging + ds_read_b128 frag reads (r5).
// Epilogue: NO atomics — writes fp16 (round-down) min of d~ = ||e||^2 - 2 x.e
// per (row, 16-col cell) into pmin[8192][512]. Error bound handled in refine.
// (256,3): ~70 VGPR + 64 AGPR < 170 cap -> no spill (r3 lesson: watch WRITE_SIZE).
__global__ __launch_bounds__(256, 3) void mfma_pmin_kernel(
    const unsigned short* __restrict__ X0p, const unsigned short* __restrict__ E0p,
    const float* __restrict__ esq, unsigned short* __restrict__ pmin) {
  __shared__ unsigned short lds[8192];  // 16 KB: X0 segs 0-7, E0 segs 8-15

  const int tid = threadIdx.x;
  const int wid = tid >> 6;
  const int lane = tid & 63;
  const int li = lane & 15;
  const int lh = (lane >> 4) & 1;
  const int lq2 = lane >> 5;

  const int bid = blockIdx.x;
  const int nb = (bid & 7) * 8 + ((bid >> 3) & 7);  // XCD-sharded N
  const int mb = bid >> 6;
  const int m0 = mb * 128, n0 = nb * 128;
  const int wm = (wid >> 1) * 64, wn = (wid & 1) * 64;

  const int r_st = lane >> 2;
  const int kp_st = ((lane & 3) - (r_st >> 1)) & 3;
  const int sw_k0 = (li * 4 + ((lq2 + (li >> 1)) & 3)) * 8;
  const int sw_k1 = (li * 4 + ((2 + lq2 + (li >> 1)) & 3)) * 8;

  f32x16 acc[2][2];
#pragma unroll
  for (int a = 0; a < 2; ++a)
#pragma unroll
    for (int b = 0; b < 2; ++b)
#pragma unroll
      for (int r = 0; r < 16; ++r) acc[a][b][r] = 0.0f;

  const int aseg = (wm >> 4) + lh;  // + mt*2
  const int bseg = (wn >> 4) + lh;  // + nt*2

  for (int kc = 0; kc < 8; ++kc) {
    const int k0 = kc * 32;
    __syncthreads();
#pragma unroll
    for (int j = 0; j < 4; ++j) {
      const int tt = j * 4 + wid;   // 16 seg-loads over 4 waves
      const int tsel = tt >> 3;     // 0=X0 1=E0
      const int seg = tt & 7;
      const int rowbase = (tsel ? n0 : m0) + seg * 16 + r_st;
      const unsigned short* src = tsel ? E0p : X0p;
      load_lds16(src + (size_t)rowbase * K_TOT + k0 + kp_st * 8,
                 &lds[tsel * 4096 + seg * 512]);
    }
    __syncthreads();

    f16x8 afr[2][2];
#pragma unroll
    for (int mt = 0; mt < 2; ++mt) {
      const unsigned short* ab = &lds[(aseg + mt * 2) * 512];
      afr[mt][0] = *(const f16x8*)(ab + sw_k0);
      afr[mt][1] = *(const f16x8*)(ab + sw_k1);
    }
#pragma unroll
    for (int nt = 0; nt < 2; ++nt) {
      const unsigned short* bb = &lds[4096 + (bseg + nt * 2) * 512];
      f16x8 b0 = *(const f16x8*)(bb + sw_k0);
      f16x8 b1 = *(const f16x8*)(bb + sw_k1);
#pragma unroll
      for (int mt = 0; mt < 2; ++mt) {
        f32x16 c = acc[mt][nt];
        c = __builtin_amdgcn_mfma_f32_32x32x16_f16(afr[mt][0], b0, c, 0, 0, 0);
        c = __builtin_amdgcn_mfma_f32_32x32x16_f16(afr[mt][1], b1, c, 0, 0, 0);
        acc[mt][nt] = c;
      }
    }
  }

  // ---- epilogue: d~ = ||e||^2 - 2 x.e ; per-(row,16-col-cell) minima ----
  // C/D layout (m74/m101, r5-verified): col = lane&31, row = (r&3)+8*(r>>2)+4*lq2
  const int colbase = n0 + wn + (lane & 31);
  float ev[2];
#pragma unroll
  for (int nt = 0; nt < 2; ++nt) ev[nt] = esq[colbase + nt * 32];
  const int cellb = ((n0 + wn) >> 4) + ((lane >> 4) & 1);

#pragma unroll
  for (int mt = 0; mt < 2; ++mt) {
#pragma unroll
    for (int r = 0; r < 16; ++r) {
      const int row = m0 + wm + mt * 32 + (r & 3) + 8 * (r >> 2) + 4 * lq2;
#pragma unroll
      for (int nt = 0; nt < 2; ++nt) {
        float d = ev[nt] - 2.0f * acc[mt][nt][r];
#pragma unroll
        for (int off = 1; off < 16; off <<= 1) d = fminf(d, __shfl_xor(d, off, 64));
        if ((lane & 15) == 0)
          pmin[(size_t)row * 512 + cellb + nt * 2] =
              __half_as_ushort(__float2half_rd(d));  // round-down: stored <= true
      }
    }
  }
}

// ---------- phase-2: per-row exact refine (fp64) + fused gather ----------
// One wave per row: scan 512 fp16 cell-minima, rescan cells within m~ + M
// exactly in fp64 against the ORIGINAL fp32 data, argmin with tie->lower idx.
// M = 4*2^-10*||x||*24 + 1.2 >= 2*(fp16 dist2 err bound) + fp16-storage ulp:
// rigorous superset guarantee, expected ~1.2 cells/row rescanned.
__global__ __launch_bounds__(256) void refine_gather_kernel(
    const float* __restrict__ x, const float* __restrict__ embed,
    const float* __restrict__ xsq, const unsigned short* __restrict__ pmin,
    float* __restrict__ out) {
  const int row = blockIdx.x * 4 + (threadIdx.x >> 6);
  const int lane = threadIdx.x & 63;

  // load this row's 512 cell minima: 8 cells/lane
  const unsigned short* pm = pmin + (size_t)row * 512 + lane * 8;
  int4 raw = *reinterpret_cast<const int4*>(pm);
  unsigned short cu[8];
  *reinterpret_cast<int4*>(cu) = raw;
  float cv[8];
#pragma unroll
  for (int j = 0; j < 8; ++j) cv[j] = __half2float(__ushort_as_half(cu[j]));
  float lm = cv[0];
#pragma unroll
  for (int j = 1; j < 8; ++j) lm = fminf(lm, cv[j]);
#pragma unroll
  for (int off = 1; off < 64; off <<= 1) lm = fminf(lm, __shfl_xor(lm, off, 64));

  const float thr = lm + sqrtf(xsq[row]) * (24.0f * 4.0f / 1024.0f) + 1.2f;
  const float4 xv = reinterpret_cast<const float4*>(x + (size_t)row * K_TOT)[lane];

  double bd = 1e300;
  int bidx = 0;
#pragma unroll
  for (int j = 0; j < 8; ++j) {
    unsigned long long mask = __ballot(cv[j] < thr);
    while (mask) {
      const int b = __ffsll((long long)mask) - 1;
      mask &= mask - 1;
      const int cell = b * 8 + j;
#pragma unroll 1
      for (int i = 0; i < 16; ++i) {
        const int col = cell * 16 + i;
        float4 e4 = reinterpret_cast<const float4*>(embed + (size_t)col * K_TOT)[lane];
        double d0 = (double)xv.x - (double)e4.x;
        double d1 = (double)xv.y - (double)e4.y;
        double d2 = (double)xv.z - (double)e4.z;
        double d3 = (double)xv.w - (double)e4.w;
        double dd = d0 * d0 + d1 * d1 + d2 * d2 + d3 * d3;
#pragma unroll
        for (int off = 1; off < 64; off <<= 1) dd += __shfl_xor(dd, off, 64);
        if (dd < bd || (dd == bd && col < bidx)) { bd = dd; bidx = col; }
      }
    }
  }

  // fused gather + index write
  reinterpret_cast<float4*>(out)[(size_t)row * 64 + lane] =
      reinterpret_cast<const float4*>(embed)[(size_t)bidx * 64 + lane];
  if (lane == 0) out[(size_t)M_TOT * K_TOT + row] = (float)bidx;
}

// ================= fallback (round-1 fp32 path, known-correct) =================
#define BM 32
#define BN 64
#define KC 32
#define NQ 2
#define NPQ (N_TOT / NQ)
#define SB 72

__global__ __launch_bounds__(256) void esq_kernel(const float* __restrict__ embed,
                                                  float* __restrict__ esq) {
  const int lane = threadIdx.x & 63;
  const int wave = threadIdx.x >> 6;
  const int code = blockIdx.x * 4 + wave;
  float4 v = reinterpret_cast<const float4*>(embed + (size_t)code * K_TOT)[lane];
  float s = v.x * v.x + v.y * v.y + v.z * v.z + v.w * v.w;
#pragma unroll
  for (int off = 32; off > 0; off >>= 1) s += __shfl_xor(s, off, 64);
  if (lane == 0) esq[code] = s;
}

__global__ __launch_bounds__(256, 2) void argmin_kernel(
    const float* __restrict__ x, const float* __restrict__ embed,
    const float* __restrict__ esq, float* __restrict__ pval, int* __restrict__ pidx) {
  __shared__ float A[K_TOT][BM];
  __shared__ float Bs[KC][SB];
  const int tid = threadIdx.x;
  const int tx = tid & 15;
  const int ty = tid >> 4;
  const int q = blockIdx.x & 1;
  const int mb = blockIdx.x >> 1;
  const int m0 = mb * BM;
  const int nq0 = q * NPQ;
#pragma unroll
  for (int it = 0; it < 8; ++it) {
    int idx = it * 256 + tid;
    int row = idx >> 6;
    int k4 = idx & 63;
    float4 v = reinterpret_cast<const float4*>(x + (size_t)(m0 + row) * K_TOT)[k4];
    A[k4 * 4 + 0][row] = v.x; A[k4 * 4 + 1][row] = v.y;
    A[k4 * 4 + 2][row] = v.z; A[k4 * 4 + 3][row] = v.w;
  }
  float minv[2]; int mini[2];
#pragma unroll
  for (int r = 0; r < 2; ++r) { minv[r] = 3.4e38f; mini[r] = 0; }
  for (int ns = 0; ns < NPQ / BN; ++ns) {
    const int n0 = nq0 + ns * BN;
    float acc[2][4];
#pragma unroll
    for (int r = 0; r < 2; ++r)
#pragma unroll
      for (int c = 0; c < 4; ++c) acc[r][c] = 0.0f;
    for (int kc = 0; kc < K_TOT / KC; ++kc) {
      const int k0 = kc * KC;
      __syncthreads();
#pragma unroll
      for (int it = 0; it < 2; ++it) {
        int idx = it * 256 + tid;
        int nl = idx >> 3;
        int k4 = idx & 7;
        float4 v = reinterpret_cast<const float4*>(embed + (size_t)(n0 + nl) * K_TOT + k0)[k4];
        Bs[k4 * 4 + 0][nl] = v.x; Bs[k4 * 4 + 1][nl] = v.y;
        Bs[k4 * 4 + 2][nl] = v.z; Bs[k4 * 4 + 3][nl] = v.w;
      }
      __syncthreads();
#pragma unroll
      for (int kk = 0; kk < KC; ++kk) {
        float2 a = *reinterpret_cast<const float2*>(&A[k0 + kk][ty * 2]);
        float4 b = *reinterpret_cast<const float4*>(&Bs[kk][tx * 4]);
        acc[0][0] += a.x * b.x; acc[0][1] += a.x * b.y;
        acc[0][2] += a.x * b.z; acc[0][3] += a.x * b.w;
        acc[1][0] += a.y * b.x; acc[1][1] += a.y * b.y;
        acc[1][2] += a.y * b.z; acc[1][3] += a.y * b.w;
      }
    }
    float4 es = *reinterpret_cast<const float4*>(&esq[n0 + tx * 4]);
    float e[4] = {es.x, es.y, es.z, es.w};
#pragma unroll
    for (int r = 0; r < 2; ++r)
#pragma unroll
      for (int c = 0; c < 4; ++c) {
        float d = e[c] - 2.0f * acc[r][c];
        int id = n0 + tx * 4 + c;
        if (d < minv[r]) { minv[r] = d; mini[r] = id; }
      }
  }
#pragma unroll
  for (int r = 0; r < 2; ++r) {
    float v = minv[r]; int i = mini[r];
#pragma unroll
    for (int off = 1; off < 16; off <<= 1) {
      float vo = __shfl_xor(v, off, 64);
      int io = __shfl_xor(i, off, 64);
      if (vo < v || (vo == v && io < i)) { v = vo; i = io; }
    }
    if (tx == 0) {
      int row = m0 + ty * 2 + r;
      pval[q * M_TOT + row] = v;
      pidx[q * M_TOT + row] = i;
    }
  }
}

__global__ __launch_bounds__(256) void gather_kernel(
    const float* __restrict__ embed, const float* __restrict__ pval,
    const int* __restrict__ pidx, float* __restrict__ out) {
  const int row = blockIdx.x;
  float bv = pval[row]; int bi = pidx[row];
#pragma unroll
  for (int qq = 1; qq < NQ; ++qq) {
    float v = pval[qq * M_TOT + row];
    int i = pidx[qq * M_TOT + row];
    if (v < bv || (v == bv && i < bi)) { bv = v; bi = i; }
  }
  out[(size_t)row * K_TOT + threadIdx.x] = embed[(size_t)bi * K_TOT + threadIdx.x];
  if (threadIdx.x == 0) out[(size_t)M_TOT * K_TOT + row] = (float)bi;
}

// ================= launch =================
extern "C" void kernel_launch(void* const* d_in, const int* in_sizes, int n_in,
                              void* d_out, int out_size, void* d_ws, size_t ws_size,
                              hipStream_t stream) {
  const float* x = (const float*)d_in[0];
  const float* embed = (const float*)d_in[1];
  float* out = (float*)d_out;
  char* ws = (char*)d_ws;

  const size_t HALF_BYTES = (size_t)M_TOT * K_TOT * 2;   // 4 MB per fp16 tensor
  const size_t PMIN_BYTES = (size_t)M_TOT * 512 * 2;     // 8 MB
  const size_t need = (1u << 20) + 2 * HALF_BYTES + PMIN_BYTES;  // ~17 MB

  if (ws_size >= need) {
    float* xsq = (float*)ws;                             // 32 KB
    float* esq = (float*)(ws + 32768);                   // 32 KB
    unsigned short* X0p = (unsigned short*)(ws + (1u << 20));
    unsigned short* E0p = (unsigned short*)(ws + (1u << 20) + HALF_BYTES);
    unsigned short* pmin = (unsigned short*)(ws + (1u << 20) + 2 * HALF_BYTES);
    prep_kernel<<<4096, 256, 0, stream>>>(x, embed, X0p, E0p, xsq, esq);
    mfma_pmin_kernel<<<4096, 256, 0, stream>>>(X0p, E0p, esq, pmin);
    refine_gather_kernel<<<2048, 256, 0, stream>>>(x, embed, xsq, pmin, out);
  } else {
    float* esq = (float*)ws;
    float* pval = (float*)(ws + 32768);
    int* pidx = (int*)(ws + 32768 + NQ * 32768);
    esq_kernel<<<2048, 256, 0, stream>>>(embed, esq);
    argmin_kernel<<<512, 256, 0, stream>>>(x, embed, esq, pval, pidx);
    gather_kernel<<<M_TOT, 256, 0, stream>>>(embed, pval, pidx, out);
  }
}

// Round 9
// 150.600 us; speedup vs baseline: 1.8135x; 1.4796x over previous
//
#include <hip/hip_runtime.h>
#include <hip/hip_fp16.h>

typedef __attribute__((ext_vector_type(8))) _Float16 f16x8;
typedef __attribute__((ext_vector_type(16))) float f32x16;

#define M_TOT 8192
#define N_TOT 8192
#define K_TOT 256

__device__ __forceinline__ void load_lds16(const void* g, void* l) {
  __builtin_amdgcn_global_load_lds(
      (const __attribute__((address_space(1))) unsigned int*)g,
      (__attribute__((address_space(3))) unsigned int*)l, 16, 0, 0);
}
__device__ __forceinline__ double shfl_xor_d(double v, int m) {
  unsigned long long u = (unsigned long long)__double_as_longlong(v);
  unsigned lo = (unsigned)u, hi = (unsigned)(u >> 32);
  lo = __shfl_xor(lo, m, 64);
  hi = __shfl_xor(hi, m, 64);
  return __longlong_as_double((long long)((((unsigned long long)hi) << 32) | lo));
}

// ---------- prep: fp16 convert (row-major) + row sq-norms ----------
__global__ __launch_bounds__(256) void prep_kernel(
    const float* __restrict__ x, const float* __restrict__ embed,
    unsigned short* __restrict__ X0p, unsigned short* __restrict__ E0p,
    float* __restrict__ xsq, float* __restrict__ esq) {
  const int bid = blockIdx.x;
  const bool is_e = bid >= 2048;
  const int lb = is_e ? bid - 2048 : bid;
  const int t = lb * 256 + threadIdx.x;  // 4 elems per thread; wave == row
  const float* __restrict__ in = is_e ? embed : x;
  unsigned short* __restrict__ p0 = is_e ? E0p : X0p;
  float* __restrict__ sq = is_e ? esq : xsq;

  float4 v = reinterpret_cast<const float4*>(in)[t];
  float f[4] = {v.x, v.y, v.z, v.w};
  unsigned short h[4];
#pragma unroll
  for (int c = 0; c < 4; ++c) h[c] = __half_as_ushort(__float2half_rn(f[c]));
  ushort4 o = {h[0], h[1], h[2], h[3]};
  reinterpret_cast<ushort4*>(p0)[t] = o;

  const int lane = threadIdx.x & 63;
  float s = f[0] * f[0] + f[1] * f[1] + f[2] * f[2] + f[3] * f[3];
#pragma unroll
  for (int off = 32; off > 0; off >>= 1) s += __shfl_xor(s, off, 64);
  if (lane == 0) sq[lb * 4 + (threadIdx.x >> 6)] = s;
}

// ---------- phase-1: single-pass fp16 MFMA, SWAPPED operands (A=E, B=X) ----------
// 128 codes x 128 rows tile, 4 waves 2x2 (we = e-half, wx = x-half), BK=64,
// LDS 32 KB. C/D: x-row = lane&31, e-col = (r&3)+8*(r>>2)+4*(lane>>5)
// -> per-(row, 16-col cell) min = 7 in-lane VALU fmin + ONE shfl_xor(32),
// 4 cells pack into one ushort4 store. (r8's 256-shfl epilogue was ~34 us.)
// (256,3): 64 AGPR acc + ~90 VGPR < 170 cap -> no spill (watch WRITE_SIZE).
__global__ __launch_bounds__(256, 3) void mfma_pmin_kernel(
    const unsigned short* __restrict__ X0p, const unsigned short* __restrict__ E0p,
    const float* __restrict__ esq, unsigned short* __restrict__ pmin) {
  __shared__ unsigned short lds[16384];  // 32 KB: E [ksl][seg] at 0, X at 8192

  const int tid = threadIdx.x;
  const int wid = tid >> 6;
  const int lane = tid & 63;
  const int li = lane & 15;
  const int lh = (lane >> 4) & 1;
  const int lq2 = lane >> 5;

  const int bid = blockIdx.x;
  const int nb = (bid & 7) * 8 + ((bid >> 3) & 7);  // XCD-sharded codes
  const int mb = bid >> 6;
  const int m0 = mb * 128, n0 = nb * 128;  // m = x-rows, n = codes
  const int wn = (wid >> 1) * 64, wm = (wid & 1) * 64;

  const int r_st = lane >> 2;
  const int kp_st = ((lane & 3) - (r_st >> 1)) & 3;
  const int sw_k0 = (li * 4 + ((lq2 + (li >> 1)) & 3)) * 8;
  const int sw_k1 = (li * 4 + ((2 + lq2 + (li >> 1)) & 3)) * 8;

  f32x16 acc[2][2];  // [et][xt]
#pragma unroll
  for (int a = 0; a < 2; ++a)
#pragma unroll
    for (int b = 0; b < 2; ++b)
#pragma unroll
      for (int r = 0; r < 16; ++r) acc[a][b][r] = 0.0f;

  const int eseg = (wn >> 4) + lh;  // + et*2
  const int xseg = (wm >> 4) + lh;  // + xt*2

  for (int kc = 0; kc < 4; ++kc) {
    const int k0 = kc * 64;
    __syncthreads();
#pragma unroll
    for (int j = 0; j < 8; ++j) {  // 32 seg-loads over 4 waves
      const int tt = j * 4 + wid;
      const int tsel = tt >> 4;    // 0=E 1=X
      const int u = tt & 15;
      const int ksl = u >> 3, seg = u & 7;
      const int rowbase = (tsel ? m0 : n0) + seg * 16 + r_st;
      const unsigned short* src = tsel ? X0p : E0p;
      load_lds16(src + (size_t)rowbase * K_TOT + k0 + ksl * 32 + kp_st * 8,
                 &lds[tsel * 8192 + ksl * 4096 + seg * 512]);
    }
    __syncthreads();

#pragma unroll
    for (int ksl = 0; ksl < 2; ++ksl) {
      const unsigned short* Eb = &lds[ksl * 4096];
      const unsigned short* Xb = &lds[8192 + ksl * 4096];
      f16x8 ef[2][2];
#pragma unroll
      for (int et = 0; et < 2; ++et) {
        const unsigned short* eb = Eb + (eseg + et * 2) * 512;
        ef[et][0] = *(const f16x8*)(eb + sw_k0);
        ef[et][1] = *(const f16x8*)(eb + sw_k1);
      }
#pragma unroll
      for (int xt = 0; xt < 2; ++xt) {
        const unsigned short* xb = Xb + (xseg + xt * 2) * 512;
        f16x8 xf0 = *(const f16x8*)(xb + sw_k0);
        f16x8 xf1 = *(const f16x8*)(xb + sw_k1);
#pragma unroll
        for (int et = 0; et < 2; ++et) {
          f32x16 c = acc[et][xt];
          c = __builtin_amdgcn_mfma_f32_32x32x16_f16(ef[et][0], xf0, c, 0, 0, 0);
          c = __builtin_amdgcn_mfma_f32_32x32x16_f16(ef[et][1], xf1, c, 0, 0, 0);
          acc[et][xt] = c;
        }
      }
    }
  }

  // ---- epilogue: d~ = ||e||^2 - 2 x.e ; per-(row,cell16) min, in-lane over r ----
  float es[2][16];
#pragma unroll
  for (int et = 0; et < 2; ++et)
#pragma unroll
    for (int r = 0; r < 16; ++r)
      es[et][r] = esq[n0 + wn + et * 32 + (r & 3) + 8 * (r >> 2) + 4 * lq2];

#pragma unroll
  for (int xt = 0; xt < 2; ++xt) {
    unsigned short outv[4];
#pragma unroll
    for (int et = 0; et < 2; ++et) {
#pragma unroll
      for (int cell = 0; cell < 2; ++cell) {  // cell0: r 0..7 (cols 0-15), cell1: r 8..15
        float mval = 3.4e38f;
#pragma unroll
        for (int rr = 0; rr < 8; ++rr) {
          const int r = cell * 8 + rr;
          mval = fminf(mval, es[et][r] - 2.0f * acc[et][xt][r]);
        }
        mval = fminf(mval, __shfl_xor(mval, 32, 64));  // combine lq2 col-halves
        outv[et * 2 + cell] = __half_as_ushort(__float2half_rd(mval));
      }
    }
    if (lq2 == 0) {
      const int xrow = m0 + wm + xt * 32 + (lane & 31);
      *reinterpret_cast<ushort4*>(&pmin[(size_t)xrow * 512 + ((n0 + wn) >> 4)]) =
          *reinterpret_cast<ushort4*>(outv);
    }
  }
}

// ---------- phase-2: per-row exact refine (fp64, lane-parallel) + fused gather ----------
// Wave per row. Candidate cell: lane (c=lane&15, q=lane>>4) computes col=cell*16+c's
// partial fp64 dot over k in [64q,64q+64) -> 2-level q-reduce + 4-level c-reduce
// w/ index (12 swizzles TOTAL per cell vs r8's 12 per COLUMN). Margin formula
// unchanged (validated r8). Tie -> lower idx = numpy first-occurrence.
__global__ __launch_bounds__(256) void refine_gather_kernel(
    const float* __restrict__ x, const float* __restrict__ embed,
    const float* __restrict__ xsq, const unsigned short* __restrict__ pmin,
    float* __restrict__ out) {
  const int row = blockIdx.x * 4 + (threadIdx.x >> 6);
  const int lane = threadIdx.x & 63;

  const unsigned short* pm = pmin + (size_t)row * 512 + lane * 8;
  int4 raw = *reinterpret_cast<const int4*>(pm);
  unsigned short cu[8];
  *reinterpret_cast<int4*>(cu) = raw;
  float cv[8];
#pragma unroll
  for (int j = 0; j < 8; ++j) cv[j] = __half2float(__ushort_as_half(cu[j]));
  float lm = cv[0];
#pragma unroll
  for (int j = 1; j < 8; ++j) lm = fminf(lm, cv[j]);
#pragma unroll
  for (int off = 1; off < 64; off <<= 1) lm = fminf(lm, __shfl_xor(lm, off, 64));

  const float thr = lm + sqrtf(xsq[row]) * (96.0f / 1024.0f) + 1.2f;

  const int c = lane & 15, q = lane >> 4;
  const float* xp = x + (size_t)row * K_TOT + q * 64;

  double bd = 1e300;
  int bidx = 1 << 30;
#pragma unroll
  for (int j = 0; j < 8; ++j) {
    unsigned long long mask = __ballot(cv[j] < thr);
    while (mask) {
      const int b = __ffsll((long long)mask) - 1;
      mask &= mask - 1;
      const int cell = b * 8 + j;
      const int col = cell * 16 + c;
      const float* ep = embed + (size_t)col * K_TOT + q * 64;
      double dd = 0.0;
#pragma unroll
      for (int i = 0; i < 16; ++i) {
        float4 e4 = reinterpret_cast<const float4*>(ep)[i];
        float4 x4 = reinterpret_cast<const float4*>(xp)[i];
        double d0 = (double)x4.x - (double)e4.x;
        double d1 = (double)x4.y - (double)e4.y;
        double d2 = (double)x4.z - (double)e4.z;
        double d3 = (double)x4.w - (double)e4.w;
        dd += d0 * d0 + d1 * d1 + d2 * d2 + d3 * d3;
      }
      dd += shfl_xor_d(dd, 16);  // combine q-partials
      dd += shfl_xor_d(dd, 32);
      int ci = col;
#pragma unroll
      for (int off = 1; off < 16; off <<= 1) {  // c-reduce with index
        double od = shfl_xor_d(dd, off);
        int oi = __shfl_xor(ci, off, 64);
        if (od < dd || (od == dd && oi < ci)) { dd = od; ci = oi; }
      }
      if (dd < bd || (dd == bd && ci < bidx)) { bd = dd; bidx = ci; }
    }
  }

  // fused gather + index write (bidx is wave-uniform)
  reinterpret_cast<float4*>(out)[(size_t)row * 64 + lane] =
      reinterpret_cast<const float4*>(embed)[(size_t)bidx * 64 + lane];
  if (lane == 0) out[(size_t)M_TOT * K_TOT + row] = (float)bidx;
}

// ================= fallback (round-1 fp32 path, known-correct) =================
#define BM 32
#define BN 64
#define KC 32
#define NQ 2
#define NPQ (N_TOT / NQ)
#define SB 72

__global__ __launch_bounds__(256) void esq_kernel(const float* __restrict__ embed,
                                                  float* __restrict__ esq) {
  const int lane = threadIdx.x & 63;
  const int wave = threadIdx.x >> 6;
  const int code = blockIdx.x * 4 + wave;
  float4 v = reinterpret_cast<const float4*>(embed + (size_t)code * K_TOT)[lane];
  float s = v.x * v.x + v.y * v.y + v.z * v.z + v.w * v.w;
#pragma unroll
  for (int off = 32; off > 0; off >>= 1) s += __shfl_xor(s, off, 64);
  if (lane == 0) esq[code] = s;
}

__global__ __launch_bounds__(256, 2) void argmin_kernel(
    const float* __restrict__ x, const float* __restrict__ embed,
    const float* __restrict__ esq, float* __restrict__ pval, int* __restrict__ pidx) {
  __shared__ float A[K_TOT][BM];
  __shared__ float Bs[KC][SB];
  const int tid = threadIdx.x;
  const int tx = tid & 15;
  const int ty = tid >> 4;
  const int q = blockIdx.x & 1;
  const int mb = blockIdx.x >> 1;
  const int m0 = mb * BM;
  const int nq0 = q * NPQ;
#pragma unroll
  for (int it = 0; it < 8; ++it) {
    int idx = it * 256 + tid;
    int row = idx >> 6;
    int k4 = idx & 63;
    float4 v = reinterpret_cast<const float4*>(x + (size_t)(m0 + row) * K_TOT)[k4];
    A[k4 * 4 + 0][row] = v.x; A[k4 * 4 + 1][row] = v.y;
    A[k4 * 4 + 2][row] = v.z; A[k4 * 4 + 3][row] = v.w;
  }
  float minv[2]; int mini[2];
#pragma unroll
  for (int r = 0; r < 2; ++r) { minv[r] = 3.4e38f; mini[r] = 0; }
  for (int ns = 0; ns < NPQ / BN; ++ns) {
    const int n0 = nq0 + ns * BN;
    float acc[2][4];
#pragma unroll
    for (int r = 0; r < 2; ++r)
#pragma unroll
      for (int c = 0; c < 4; ++c) acc[r][c] = 0.0f;
    for (int kc = 0; kc < K_TOT / KC; ++kc) {
      const int k0 = kc * KC;
      __syncthreads();
#pragma unroll
      for (int it = 0; it < 2; ++it) {
        int idx = it * 256 + tid;
        int nl = idx >> 3;
        int k4 = idx & 7;
        float4 v = reinterpret_cast<const float4*>(embed + (size_t)(n0 + nl) * K_TOT + k0)[k4];
        Bs[k4 * 4 + 0][nl] = v.x; Bs[k4 * 4 + 1][nl] = v.y;
        Bs[k4 * 4 + 2][nl] = v.z; Bs[k4 * 4 + 3][nl] = v.w;
      }
      __syncthreads();
#pragma unroll
      for (int kk = 0; kk < KC; ++kk) {
        float2 a = *reinterpret_cast<const float2*>(&A[k0 + kk][ty * 2]);
        float4 b = *reinterpret_cast<const float4*>(&Bs[kk][tx * 4]);
        acc[0][0] += a.x * b.x; acc[0][1] += a.x * b.y;
        acc[0][2] += a.x * b.z; acc[0][3] += a.x * b.w;
        acc[1][0] += a.y * b.x; acc[1][1] += a.y * b.y;
        acc[1][2] += a.y * b.z; acc[1][3] += a.y * b.w;
      }
    }
    float4 es = *reinterpret_cast<const float4*>(&esq[n0 + tx * 4]);
    float e[4] = {es.x, es.y, es.z, es.w};
#pragma unroll
    for (int r = 0; r < 2; ++r)
#pragma unroll
      for (int c = 0; c < 4; ++c) {
        float d = e[c] - 2.0f * acc[r][c];
        int id = n0 + tx * 4 + c;
        if (d < minv[r]) { minv[r] = d; mini[r] = id; }
      }
  }
#pragma unroll
  for (int r = 0; r < 2; ++r) {
    float v = minv[r]; int i = mini[r];
#pragma unroll
    for (int off = 1; off < 16; off <<= 1) {
      float vo = __shfl_xor(v, off, 64);
      int io = __shfl_xor(i, off, 64);
      if (vo < v || (vo == v && io < i)) { v = vo; i = io; }
    }
    if (tx == 0) {
      int row = m0 + ty * 2 + r;
      pval[q * M_TOT + row] = v;
      pidx[q * M_TOT + row] = i;
    }
  }
}

__global__ __launch_bounds__(256) void gather_kernel(
    const float* __restrict__ embed, const float* __restrict__ pval,
    const int* __restrict__ pidx, float* __restrict__ out) {
  const int row = blockIdx.x;
  float bv = pval[row]; int bi = pidx[row];
#pragma unroll
  for (int qq = 1; qq < NQ; ++qq) {
    float v = pval[qq * M_TOT + row];
    int i = pidx[qq * M_TOT + row];
    if (v < bv || (v == bv && i < bi)) { bv = v; bi = i; }
  }
  out[(size_t)row * K_TOT + threadIdx.x] = embed[(size_t)bi * K_TOT + threadIdx.x];
  if (threadIdx.x == 0) out[(size_t)M_TOT * K_TOT + row] = (float)bi;
}

// ================= launch =================
extern "C" void kernel_launch(void* const* d_in, const int* in_sizes, int n_in,
                              void* d_out, int out_size, void* d_ws, size_t ws_size,
                              hipStream_t stream) {
  const float* x = (const float*)d_in[0];
  const float* embed = (const float*)d_in[1];
  float* out = (float*)d_out;
  char* ws = (char*)d_ws;

  const size_t HALF_BYTES = (size_t)M_TOT * K_TOT * 2;   // 4 MB per fp16 tensor
  const size_t PMIN_BYTES = (size_t)M_TOT * 512 * 2;     // 8 MB
  const size_t need = (1u << 20) + 2 * HALF_BYTES + PMIN_BYTES;  // ~17 MB

  if (ws_size >= need) {
    float* xsq = (float*)ws;                             // 32 KB
    float* esq = (float*)(ws + 32768);                   // 32 KB
    unsigned short* X0p = (unsigned short*)(ws + (1u << 20));
    unsigned short* E0p = (unsigned short*)(ws + (1u << 20) + HALF_BYTES);
    unsigned short* pmin = (unsigned short*)(ws + (1u << 20) + 2 * HALF_BYTES);
    prep_kernel<<<4096, 256, 0, stream>>>(x, embed, X0p, E0p, xsq, esq);
    mfma_pmin_kernel<<<4096, 256, 0, stream>>>(X0p, E0p, esq, pmin);
    refine_gather_kernel<<<2048, 256, 0, stream>>>(x, embed, xsq, pmin, out);
  } else {
    float* esq = (float*)ws;
    float* pval = (float*)(ws + 32768);
    int* pidx = (int*)(ws + 32768 + NQ * 32768);
    esq_kernel<<<2048, 256, 0, stream>>>(embed, esq);
    argmin_kernel<<<512, 256, 0, stream>>>(x, embed, esq, pval, pidx);
    gather_kernel<<<M_TOT, 256, 0, stream>>>(embed, pval, pidx, out);
  }
}